// Round 8
// baseline (197.926 us; speedup 1.0000x reference)
//
#include <hip/hip_runtime.h>
#include <stdint.h>

#define N_DIM 4096
#define B_DIM 64
#define BN (B_DIM * N_DIM)        // 262144

typedef __bf16 bf16x8 __attribute__((ext_vector_type(8)));
typedef float floatx4 __attribute__((ext_vector_type(4)));

union FragU { uint4 u; bf16x8 h; };

#define AS1 __attribute__((address_space(1)))
#define AS3 __attribute__((address_space(3)))

__device__ __forceinline__ void gll16(const void* gp, void* lp) {
    // per-lane global src -> wave-uniform LDS base + lane*16
    __builtin_amdgcn_global_load_lds((const AS1 void*)gp, (AS3 void*)lp, 16, 0, 0);
}

__device__ __forceinline__ unsigned short f2bf_rne(float f) {
    unsigned int u = __float_as_uint(f);
    u += 0x7fffu + ((u >> 16) & 1u);
    return (unsigned short)(u >> 16);
}

// c = Vmag*cos, s = Vmag*sin packed bf16 in MFMA B-frag order
// idx = ((j>>3)*64 + b)*8 + (j&7); also zero the X/Y atomic accumulators.
__global__ __launch_bounds__(256) void pf_prep(
        const float* __restrict__ Vmag, const float* __restrict__ Vang,
        unsigned short* __restrict__ c_pk, unsigned short* __restrict__ s_pk,
        float* __restrict__ XY) {
    int idx = blockIdx.x * 256 + threadIdx.x;   // = b*4096 + j
    int b = idx >> 12;
    int j = idx & 4095;
    float sv, cv;
    sincosf(Vang[idx], &sv, &cv);
    float v = Vmag[idx];
    int p = (((j >> 3) << 6) + b) * 8 + (j & 7);
    c_pk[p] = f2bf_rne(v * cv);
    s_pk[p] = f2bf_rne(v * sv);
    XY[idx] = 0.f;            // X partial accumulator [b][i]
    XY[idx + BN] = 0.f;       // Y partial accumulator
}

// Occupancy-first redesign. Invariant across R0-R7 (53-74us): 1024-thread
// blocks at 1 block/CU, Occupancy 36-40% — any stall (barrier drain,
// conservative compiler vmcnt, LDS latency) idled the WHOLE CU; R1's warm
// dispatches (2 MB HBM, same 55us) proved the kernel was never HBM-bound.
// Now: 4-wave blocks, each wave owns an independent 16x16 output tile (no
// cross-wave reduction), LDS 16 KB, VGPR capped 64 -> up to 8 blocks/CU;
// grid 1024 = 256 rowblocks x 4 K-splits -> 4 resident blocks/CU whose
// barrier/memory stalls mutually overlap.
// A (G,B rows) staged via global_load_lds, coalesced (4 rows x 256 B per
// instr), XOR slot-swizzle on the GLOBAL source (rule 21) so fragment
// ds_read_b128 (16 rows at same slot) is bank-conflict-free (2-way only).
// cs fragments loaded directly from global (compact pattern, L2-resident).
// X = G*c + B*s ; Y = G*s - B*c; K-split partials via fp32 atomicAdd.
#define BUFB 8192     // one chunk: G 16x256B (4 KB) + B (4 KB)
#define BOFF 4096
__global__ __launch_bounds__(256, 8) void pf_gemm(
        const float* __restrict__ G, const float* __restrict__ Bm,
        const unsigned short* __restrict__ c_pk, const unsigned short* __restrict__ s_pk,
        float* __restrict__ XY) {
    __shared__ __align__(16) char lds[2 * BUFB];   // 16 KB
    const int tid = threadIdx.x;
    const int wave = tid >> 6;        // 0..3 = col tile nt
    const int lane = tid & 63;
    const int n = lane & 15;          // A row / B,C/D col
    const int quad = lane >> 4;       // k-subgroup
    const int rb = blockIdx.x & 255;  // row block
    const int kq = blockIdx.x >> 8;   // K quarter
    const int i0 = rb << 4;           // 16 rows per block
    const int k0 = kq << 10;          // K base (floats)

    // ---- staging: wave stages G rows [4w,4w+4) and B rows (1 KB each) ----
    const int sr = (wave << 2) + quad;            // staged row 0..15
    const int sj = n ^ (sr & 7);                  // swizzled source slot
    const float* gsrc = G  + (size_t)(i0 + sr) * N_DIM + k0 + sj * 4;
    const float* bsrc = Bm + (size_t)(i0 + sr) * N_DIM + k0 + sj * 4;
    char* stgG = lds + wave * 1024;               // + buf
    char* stgB = lds + BOFF + wave * 1024;

    // ---- cs fragment base: kgroup = kq*128 + ch*8 + kk*4 + quad ----
    const unsigned short* cp0 = c_pk + ((size_t)(kq * 128 + quad) * 64 + (wave << 4) + n) * 8;
    const unsigned short* sp0 = s_pk + ((size_t)(kq * 128 + quad) * 64 + (wave << 4) + n) * 8;

    const int m7 = n & 7;
    const int arow = n << 8;          // fragment row base (bytes)

    floatx4 accX = (floatx4){0.f, 0.f, 0.f, 0.f};
    floatx4 accY = (floatx4){0.f, 0.f, 0.f, 0.f};

    // prologue: stage chunk 0 into buffer 0
    gll16(gsrc, stgG);
    gll16(bsrc, stgB);

    for (int ch = 0; ch < 16; ++ch) {
        const int buf = (ch & 1) * BUFB;
        __syncthreads();              // chunk ch resident; prev reads done
                                      // (drain overlaps across 4+ blocks/CU)
        if (ch < 15) {                // stage chunk ch+1 into other buffer
            const int nb = ((ch + 1) & 1) * BUFB;
            gll16(gsrc + (ch + 1) * 64, stgG + nb);
            gll16(bsrc + (ch + 1) * 64, stgB + nb);
        }

        const char* base = lds + buf;
        #pragma unroll
        for (int kk = 0; kk < 2; ++kk) {
            // A fragments: slots kk*8+2q, +1 (XOR-swizzled), fp32 -> bf16
            const int s = (kk << 3) + (quad << 1);
            const int j0 = s ^ m7;
            const int j1 = (s + 1) ^ m7;
            float4 g0 = *(const float4*)(base + arow + j0 * 16);
            float4 g1 = *(const float4*)(base + arow + j1 * 16);
            float4 h0 = *(const float4*)(base + BOFF + arow + j0 * 16);
            float4 h1 = *(const float4*)(base + BOFF + arow + j1 * 16);
            bf16x8 ag, ah;
            ag[0] = (__bf16)g0.x; ag[1] = (__bf16)g0.y; ag[2] = (__bf16)g0.z; ag[3] = (__bf16)g0.w;
            ag[4] = (__bf16)g1.x; ag[5] = (__bf16)g1.y; ag[6] = (__bf16)g1.z; ag[7] = (__bf16)g1.w;
            ah[0] = (__bf16)h0.x; ah[1] = (__bf16)h0.y; ah[2] = (__bf16)h0.z; ah[3] = (__bf16)h0.w;
            ah[4] = (__bf16)h1.x; ah[5] = (__bf16)h1.y; ah[6] = (__bf16)h1.z; ah[7] = (__bf16)h1.w;

            // cs fragments (direct global, L2-resident)
            FragU cf, sf, nf;
            cf.u = *(const uint4*)(cp0 + (size_t)ch * 4096 + kk * 2048);
            sf.u = *(const uint4*)(sp0 + (size_t)ch * 4096 + kk * 2048);
            nf.u.x = cf.u.x ^ 0x80008000u;
            nf.u.y = cf.u.y ^ 0x80008000u;
            nf.u.z = cf.u.z ^ 0x80008000u;
            nf.u.w = cf.u.w ^ 0x80008000u;

            accX = __builtin_amdgcn_mfma_f32_16x16x32_bf16(ag, cf.h, accX, 0, 0, 0);
            accY = __builtin_amdgcn_mfma_f32_16x16x32_bf16(ah, nf.h, accY, 0, 0, 0);
            accX = __builtin_amdgcn_mfma_f32_16x16x32_bf16(ah, sf.h, accX, 0, 0, 0);
            accY = __builtin_amdgcn_mfma_f32_16x16x32_bf16(ag, sf.h, accY, 0, 0, 0);
        }
    }

    // K-split partial accumulation; wave's tile is private -> no reduction.
    // C/D layout: col(b)=lane&15, row(m)=quad*4+rr
    float* Xg = XY;
    float* Yg = XY + BN;
    const int ib = i0 + (quad << 2);
    const int bb = (wave << 4) + n;
    #pragma unroll
    for (int rr = 0; rr < 4; ++rr) {
        atomicAdd(Xg + (size_t)bb * N_DIM + ib + rr, accX[rr]);
        atomicAdd(Yg + (size_t)bb * N_DIM + ib + rr, accY[rr]);
    }
}

// fused epilogue: res_P/res_Q from X,Y partial sums
__global__ __launch_bounds__(256) void pf_epi(
        const float* __restrict__ Vmag, const float* __restrict__ Vang,
        const float* __restrict__ P_in, const float* __restrict__ Q_in,
        const float* __restrict__ XY, float* __restrict__ out) {
    int idx = blockIdx.x * 256 + threadIdx.x;   // = b*4096 + i
    float X = XY[idx];
    float Y = XY[idx + BN];
    float sv, cv;
    sincosf(Vang[idx], &sv, &cv);
    float v = Vmag[idx];
    float c = v * cv;
    float s = v * sv;
    out[idx] = c * X + s * Y - P_in[idx];            // res_P
    out[idx + BN] = s * X - c * Y - Q_in[idx];       // res_Q
}

extern "C" void kernel_launch(void* const* d_in, const int* in_sizes, int n_in,
                              void* d_out, int out_size, void* d_ws, size_t ws_size,
                              hipStream_t stream) {
    const float* Vmag = (const float*)d_in[0];
    const float* Vang = (const float*)d_in[1];
    const float* P_in = (const float*)d_in[2];
    const float* Q_in = (const float*)d_in[3];
    const float* G    = (const float*)d_in[4];
    const float* Bm   = (const float*)d_in[5];
    float* out = (float*)d_out;

    char* ws = (char*)d_ws;
    unsigned short* c_pk = (unsigned short*)(ws);                    // 512 KB
    unsigned short* s_pk = (unsigned short*)(ws + (512u << 10));     // 512 KB
    float* XY = (float*)(ws + (1u << 20));                           // 2 MB (X then Y)

    hipLaunchKernelGGL(pf_prep, dim3(BN / 256), dim3(256), 0, stream,
                       Vmag, Vang, c_pk, s_pk, XY);
    hipLaunchKernelGGL(pf_gemm, dim3(1024), dim3(256), 0, stream,
                       G, Bm, c_pk, s_pk, XY);
    hipLaunchKernelGGL(pf_epi, dim3(BN / 256), dim3(256), 0, stream,
                       Vmag, Vang, P_in, Q_in, XY, out);
}